// Round 5
// baseline (1095.684 us; speedup 1.0000x reference)
//
#include <hip/hip_runtime.h>

// VectorQuantizer: B=65536 rows, D=256, K=1024 codes.
// d_in[0] = inputs (B,D) fp32 ; d_in[1] = W (K,D) fp32
// d_out = [quantized_st (B*D)] [loss] [perplexity]  (fp32)
//
// argmin_k (||w_k||^2 - 2 x.w_k) via fp16 MFMA (fp32 accum).
// Round-5 structure (post-mortem of 3 latency-crippled B-from-L2 rounds):
//  - A (X) fragments live in REGISTERS for the whole kernel (wave w owns rows
//    w*16..+15: 8 x h16x8 = 32 VGPRs). No A LDS traffic, argmin is wave-local.
//  - B (codebook) streamed through LDS in 16KB slices (8 n-tiles x 2 ks),
//    double-buffered, staged with global_load_lds width=16 (m97 feed path),
//    one barrier per slice, 16 MFMAs/wave between barriers.
//  - NO __launch_bounds__ cap: gfx950 unified VGPR/AGPR file means the cap
//    applies to the SUM; rounds 3/4 proved capping causes catastrophic
//    scratch spill (symmetric FETCH/WRITE inflation). Budget ~110 regs.
// quantized_st == W[idx] numerically; loss from fp16 A regs (abs err ~2e-3,
// scalar threshold ~19.6). Finalize fused via last-block done-counter.

using h16   = _Float16;
using h16x8 = __attribute__((ext_vector_type(8))) _Float16;
using f32x4 = __attribute__((ext_vector_type(4))) float;

#define W_SCALE 1024.0f          // keep fp16 W out of denormal range
#define W_UNSCALE2 0.001953125f  // 2 / 1024, exact power of two
#define SCORE_BIAS 0.25f         // scores in [-0.1,0.1] -> biased always > 0

// async global->LDS, 16B/lane; LDS dest = wave-uniform base + lane*16
__device__ __forceinline__ void gll16(const void* g, void* l) {
  __builtin_amdgcn_global_load_lds(
      (const __attribute__((address_space(1))) unsigned int*)g,
      (__attribute__((address_space(3))) unsigned int*)l, 16, 0, 0);
}

// ---------------- kernel 1: pack W -> fp16 slice-major fragment order + ||w||^2 + ws init ----
// Slice u = chunk*4 + kspair (32 slices of 16KB). Within slice:
//   offset(h16) = ((ksl*8 + t_loc)*64 + quad*16 + lm_c)*8 + j
// where code = (chunk*8 + t_loc)*16 + lm_c, d = (kspair*2+ksl)*32 + quad*8 + j.
__global__ __launch_bounds__(64) void vq_wconv(const float* __restrict__ W,
                                               h16* __restrict__ Whp2,
                                               float* __restrict__ wws,
                                               int* __restrict__ wsInit) {
  const int t = threadIdx.x;
  if (blockIdx.x == 0) {  // zero loss_sum, done, counts (bytes 0..4351 of ws)
#pragma unroll
    for (int i = 0; i < 17; ++i) wsInit[i * 64 + t] = 0;
  }
  const int code = blockIdx.x * 2 + (t >> 5);  // 2 codes per block
  const int j = t & 31;                        // d-octet index
  const int d0 = j * 8;
  float4 v0 = *(const float4*)(W + (size_t)code * 256 + d0);
  float4 v1 = *(const float4*)(W + (size_t)code * 256 + d0 + 4);
  h16x8 h;
  h[0] = (h16)(v0.x * W_SCALE); h[1] = (h16)(v0.y * W_SCALE);
  h[2] = (h16)(v0.z * W_SCALE); h[3] = (h16)(v0.w * W_SCALE);
  h[4] = (h16)(v1.x * W_SCALE); h[5] = (h16)(v1.y * W_SCALE);
  h[6] = (h16)(v1.z * W_SCALE); h[7] = (h16)(v1.w * W_SCALE);
  const int ks = j >> 2, quad = j & 3;
  const int ksl = ks & 1, p = ks >> 1;
  const int tcode = code >> 4, c = tcode >> 3, tloc = tcode & 7, lmc = code & 15;
  const int u = c * 4 + p;
  *(h16x8*)(Whp2 + (size_t)u * 8192 + ((ksl * 8 + tloc) * 64 + quad * 16 + lmc) * 8) = h;
  float ss = v0.x * v0.x + v0.y * v0.y + v0.z * v0.z + v0.w * v0.w
           + v1.x * v1.x + v1.y * v1.y + v1.z * v1.z + v1.w * v1.w;
#pragma unroll
  for (int m = 1; m <= 16; m <<= 1) ss += __shfl_xor(ss, m);  // within 32-lane half
  if (j == 0) wws[code] = ss + SCORE_BIAS;  // pre-biased for packed-key argmin
}

// ---------------- kernel 2: scores + argmin + output + loss + histogram + finalize ----------
// Block: 64 rows x all 1024 codes, 256 threads = 4 waves (wave w: rows w*16..+15).
// mfma_f32_16x16x32_f16: A[m=lm][k=quad*8+j], B[k=quad*8+j][n=lm],
//                        D[row=quad*4+reg][col=lm]  (verified rounds 1-4)
__global__ void vq_main(const float* __restrict__ X,
                        const h16* __restrict__ Whp2,
                        const float* __restrict__ wws,
                        const float* __restrict__ W,
                        float* __restrict__ out,
                        float* __restrict__ loss_sum,
                        int* __restrict__ done,
                        int* __restrict__ counts) {
  __shared__ h16 Bs[2][8192];  // 2 x 16 KB double buffer
  __shared__ int sIdx[64];
  __shared__ float redF[4];
  __shared__ int lastFlag;
  const int tid = threadIdx.x;
  const int lane = tid & 63;
  const int wid = tid >> 6;
  const int lm = lane & 15;
  const int quad = lane >> 4;
  const int rowBase = blockIdx.x * 64;

  // kick off slice-0 staging first so the DMA overlaps the A-fragment loads
#pragma unroll
  for (int i = 0; i < 4; ++i)
    gll16(Whp2 + (size_t)(wid * 4 + i) * 512 + lane * 8, &Bs[0][(wid * 4 + i) * 512]);

  // A fragments: lane (quad,lm) holds row rowBase + wid*16 + lm,
  // d = ks*32 + quad*8 + j  (fp32 -> fp16, scaled implicitly by 1 — X unscaled)
  h16x8 A[8];
  const float* xrow = X + (size_t)(rowBase + wid * 16 + lm) * 256;
#pragma unroll
  for (int ks = 0; ks < 8; ++ks) {
    const int d0 = ks * 32 + quad * 8;
    float4 v0 = *(const float4*)(xrow + d0);
    float4 v1 = *(const float4*)(xrow + d0 + 4);
    h16x8 h;
    h[0] = (h16)v0.x; h[1] = (h16)v0.y; h[2] = (h16)v0.z; h[3] = (h16)v0.w;
    h[4] = (h16)v1.x; h[5] = (h16)v1.y; h[6] = (h16)v1.z; h[7] = (h16)v1.w;
    A[ks] = h;
  }

  f32x4 acc[8];
#pragma unroll
  for (int t = 0; t < 8; ++t) { f32x4 z = {0.f, 0.f, 0.f, 0.f}; acc[t] = z; }
  unsigned bestK[4];
#pragma unroll
  for (int r = 0; r < 4; ++r) bestK[r] = 0xFFFFFFFFu;

  __syncthreads();  // slice 0 resident (compiler drains vmcnt before barrier)

  // 32 slices: slice u = chunk (u>>2) , ks-pair (u&3). One barrier per slice.
#pragma unroll 2
  for (int u = 0; u < 32; ++u) {
    const int buf = u & 1;
    if (u < 31) {  // stage next slice into the other buffer (async DMA)
      const h16* sbase = Whp2 + (size_t)(u + 1) * 8192;
#pragma unroll
      for (int i = 0; i < 4; ++i)
        gll16(sbase + (wid * 4 + i) * 512 + lane * 8, &Bs[buf ^ 1][(wid * 4 + i) * 512]);
    }
    // compute slice u: 2 ks x 8 n-tiles = 16 MFMAs per wave
#pragma unroll
    for (int ksl = 0; ksl < 2; ++ksl) {
      h16x8 a = A[(u & 3) * 2 + ksl];
#pragma unroll
      for (int t = 0; t < 8; ++t) {
        h16x8 b = *(const h16x8*)&Bs[buf][((ksl * 8 + t) * 64 + lane) * 8];
        acc[t] = __builtin_amdgcn_mfma_f32_16x16x32_f16(a, b, acc[t], 0, 0, 0);
      }
    }
    if ((u & 3) == 3) {  // chunk epilogue: fold biased scores into packed keys
      const int c = u >> 2;
#pragma unroll
      for (int t = 0; t < 8; ++t) {
        const int code = (c * 8 + t) * 16 + lm;
        const float wn = wws[code];
#pragma unroll
        for (int reg = 0; reg < 4; ++reg) {
          float s = fmaf(-W_UNSCALE2, acc[t][reg], wn);
          unsigned key = (__float_as_uint(s) & 0xFFFFFC00u) | (unsigned)code;
          bestK[reg] = min(bestK[reg], key);
        }
        f32x4 z = {0.f, 0.f, 0.f, 0.f};
        acc[t] = z;
      }
    }
    __syncthreads();  // stage(u+1) done + all waves finished reading buf
  }

  // wave-local argmin: reduce over the 16 lm columns (codes), rows stay put
#pragma unroll
  for (int m = 1; m <= 8; m <<= 1) {
#pragma unroll
    for (int reg = 0; reg < 4; ++reg)
      bestK[reg] = min(bestK[reg], (unsigned)__shfl_xor(bestK[reg], m));
  }
  if (lm == 0) {
#pragma unroll
    for (int reg = 0; reg < 4; ++reg) {
      const int row = wid * 16 + quad * 4 + reg;   // block-local row
      const int c = (int)(bestK[reg] & 1023u);
      sIdx[row] = c;
      atomicAdd(&counts[c], 1);
    }
  }
  __syncthreads();

  // output: out row = W[idx] (== x + sg(q-x) numerically); loss vs fp16 A regs
  const int myIdx = sIdx[wid * 16 + lm];
  const float* wrow = W + (size_t)myIdx * 256;
  float* orow = out + (size_t)(rowBase + wid * 16 + lm) * 256;
  float ll = 0.0f;
#pragma unroll
  for (int ks = 0; ks < 8; ++ks) {
    const int d0 = ks * 32 + quad * 8;
    float4 q0 = *(const float4*)(wrow + d0);
    float4 q1 = *(const float4*)(wrow + d0 + 4);
    h16x8 a = A[ks];
    float e0 = q0.x - (float)a[0], e1 = q0.y - (float)a[1];
    float e2 = q0.z - (float)a[2], e3 = q0.w - (float)a[3];
    float e4 = q1.x - (float)a[4], e5 = q1.y - (float)a[5];
    float e6 = q1.z - (float)a[6], e7 = q1.w - (float)a[7];
    ll += e0 * e0 + e1 * e1 + e2 * e2 + e3 * e3
        + e4 * e4 + e5 * e5 + e6 * e6 + e7 * e7;
    *(float4*)(orow + d0) = q0;
    *(float4*)(orow + d0 + 4) = q1;
  }
#pragma unroll
  for (int m = 1; m <= 32; m <<= 1) ll += __shfl_xor(ll, m);
  if (lane == 0) atomicAdd(loss_sum, ll);

  // fused finalize: last block computes loss + perplexity
  __threadfence();
  if (tid == 0) {
    int old = atomicAdd(done, 1);
    lastFlag = (old == (int)gridDim.x - 1);
  }
  __syncthreads();
  if (lastFlag) {
    float h = 0.0f;
#pragma unroll
    for (int k = tid; k < 1024; k += 256) {
      int cnt = __hip_atomic_load(&counts[k], __ATOMIC_RELAXED, __HIP_MEMORY_SCOPE_AGENT);
      float p = (float)cnt * (1.0f / 65536.0f);
      h += p * logf(p + 1e-10f);
    }
#pragma unroll
    for (int m = 1; m <= 32; m <<= 1) h += __shfl_xor(h, m);
    if (lane == 0) redF[wid] = h;
    __syncthreads();
    if (tid == 0) {
      float hs = redF[0] + redF[1] + redF[2] + redF[3];
      float ls = __hip_atomic_load(loss_sum, __ATOMIC_RELAXED, __HIP_MEMORY_SCOPE_AGENT);
      out[16777216] = ls * (1.25f / 16777216.0f);  // (1+0.25)*mean((q-x)^2)
      out[16777217] = expf(-hs);
    }
  }
}

// ---------------- launch ----------------
extern "C" void kernel_launch(void* const* d_in, const int* in_sizes, int n_in,
                              void* d_out, int out_size, void* d_ws, size_t ws_size,
                              hipStream_t stream) {
  (void)in_sizes; (void)n_in; (void)out_size; (void)ws_size;
  const float* X = (const float*)d_in[0];
  const float* W = (const float*)d_in[1];
  float* out = (float*)d_out;
  char* ws = (char*)d_ws;
  // ws layout (bytes): [0] loss_sum f32 | [4] done i32 | [256] counts i32[1024]
  //                    [4352] wws f32[1024] | [8448] Whp2 f16[262144]  => 532736 total
  float* loss_sum = (float*)ws;
  int* done = (int*)(ws + 4);
  int* counts = (int*)(ws + 256);
  float* wws = (float*)(ws + 4352);
  h16* Whp2 = (h16*)(ws + 8448);

  vq_wconv<<<512, 64, 0, stream>>>(W, Whp2, wws, (int*)ws);
  vq_main<<<1024, 256, 0, stream>>>(X, Whp2, wws, W, out, loss_sum, done, counts);
}

// Round 6
// 794.108 us; speedup vs baseline: 1.3798x; 1.3798x over previous
//
#include <hip/hip_runtime.h>

// VectorQuantizer: B=65536 rows, D=256, K=1024 codes.
// d_in[0] = inputs (B,D) fp32 ; d_in[1] = W (K,D) fp32
// d_out = [quantized_st (B*D)] [loss] [perplexity]  (fp32)
//
// argmin_k (||w_k||^2 - 2 x.w_k) via fp16 MFMA (fp32 accum).
// Structure (round 5, feed path verified correct):
//  - A (X) fragments live in REGISTERS (wave w owns rows w*16..+15,
//    8 x h16x8 = 32 VGPRs). No A LDS traffic; argmin is wave-local.
//  - B (codebook) streamed through LDS in 16KB slices (8 n-tiles x 2 ks),
//    double-buffered, staged with global_load_lds width=16 (m97 feed path),
//    one barrier per slice, 16 MFMAs/wave between barriers.
// Register environment (rounds 3/4/5 post-mortems): the gfx950 unified
// VGPR/AGPR file cap follows __launch_bounds__; NO bounds => compiler
// assumes 1024-thread workgroups => cap ~128 => catastrophic spill
// (VGPR_Count=64 signature, WRITE_SIZE +90MB). (256,2) caps at 256 unified
// regs -- the only observed clean config (round 2: VGPR=112, exact traffic).
// quantized_st == W[idx] numerically; loss from fp16 A regs (abs err ~2e-3,
// scalar threshold ~19.6). Finalize fused via last-block done-counter.

using h16   = _Float16;
using h16x8 = __attribute__((ext_vector_type(8))) _Float16;
using f32x4 = __attribute__((ext_vector_type(4))) float;

#define W_SCALE 1024.0f          // keep fp16 W out of denormal range
#define W_UNSCALE2 0.001953125f  // 2 / 1024, exact power of two
#define SCORE_BIAS 0.25f         // scores in [-0.1,0.1] -> biased always > 0

// async global->LDS, 16B/lane; LDS dest = wave-uniform base + lane*16
__device__ __forceinline__ void gll16(const void* g, void* l) {
  __builtin_amdgcn_global_load_lds(
      (const __attribute__((address_space(1))) unsigned int*)g,
      (__attribute__((address_space(3))) unsigned int*)l, 16, 0, 0);
}

// ---------------- kernel 1: pack W -> fp16 slice-major fragment order + ||w||^2 + ws init ----
// Slice u = chunk*4 + kspair (32 slices of 16KB). Within slice:
//   offset(h16) = ((ksl*8 + t_loc)*64 + quad*16 + lm_c)*8 + j
// where code = (chunk*8 + t_loc)*16 + lm_c, d = (kspair*2+ksl)*32 + quad*8 + j.
__global__ __launch_bounds__(64) void vq_wconv(const float* __restrict__ W,
                                               h16* __restrict__ Whp2,
                                               float* __restrict__ wws,
                                               int* __restrict__ wsInit) {
  const int t = threadIdx.x;
  if (blockIdx.x == 0) {  // zero loss_sum, done, counts (bytes 0..4351 of ws)
#pragma unroll
    for (int i = 0; i < 17; ++i) wsInit[i * 64 + t] = 0;
  }
  const int code = blockIdx.x * 2 + (t >> 5);  // 2 codes per block
  const int j = t & 31;                        // d-octet index
  const int d0 = j * 8;
  float4 v0 = *(const float4*)(W + (size_t)code * 256 + d0);
  float4 v1 = *(const float4*)(W + (size_t)code * 256 + d0 + 4);
  h16x8 h;
  h[0] = (h16)(v0.x * W_SCALE); h[1] = (h16)(v0.y * W_SCALE);
  h[2] = (h16)(v0.z * W_SCALE); h[3] = (h16)(v0.w * W_SCALE);
  h[4] = (h16)(v1.x * W_SCALE); h[5] = (h16)(v1.y * W_SCALE);
  h[6] = (h16)(v1.z * W_SCALE); h[7] = (h16)(v1.w * W_SCALE);
  const int ks = j >> 2, quad = j & 3;
  const int ksl = ks & 1, p = ks >> 1;
  const int tcode = code >> 4, c = tcode >> 3, tloc = tcode & 7, lmc = code & 15;
  const int u = c * 4 + p;
  *(h16x8*)(Whp2 + (size_t)u * 8192 + ((ksl * 8 + tloc) * 64 + quad * 16 + lmc) * 8) = h;
  float ss = v0.x * v0.x + v0.y * v0.y + v0.z * v0.z + v0.w * v0.w
           + v1.x * v1.x + v1.y * v1.y + v1.z * v1.z + v1.w * v1.w;
#pragma unroll
  for (int m = 1; m <= 16; m <<= 1) ss += __shfl_xor(ss, m);  // within 32-lane half
  if (j == 0) wws[code] = ss + SCORE_BIAS;  // pre-biased for packed-key argmin
}

// ---------------- kernel 2: scores + argmin + output + loss + histogram + finalize ----------
// Block: 64 rows x all 1024 codes, 256 threads = 4 waves (wave w: rows w*16..+15).
// mfma_f32_16x16x32_f16: A[m=lm][k=quad*8+j], B[k=quad*8+j][n=lm],
//                        D[row=quad*4+reg][col=lm]  (verified rounds 1-5)
__global__ __launch_bounds__(256, 2) void vq_main(const float* __restrict__ X,
                                                  const h16* __restrict__ Whp2,
                                                  const float* __restrict__ wws,
                                                  const float* __restrict__ W,
                                                  float* __restrict__ out,
                                                  float* __restrict__ loss_sum,
                                                  int* __restrict__ done,
                                                  int* __restrict__ counts) {
  __shared__ h16 Bs[2][8192];  // 2 x 16 KB double buffer
  __shared__ int sIdx[64];
  __shared__ float redF[4];
  __shared__ int lastFlag;
  const int tid = threadIdx.x;
  const int lane = tid & 63;
  const int wid = tid >> 6;
  const int lm = lane & 15;
  const int quad = lane >> 4;
  const int rowBase = blockIdx.x * 64;

  // kick off slice-0 staging first so the DMA overlaps the A-fragment loads
#pragma unroll
  for (int i = 0; i < 4; ++i)
    gll16(Whp2 + (size_t)(wid * 4 + i) * 512 + lane * 8, &Bs[0][(wid * 4 + i) * 512]);

  // A fragments: lane (quad,lm) holds row rowBase + wid*16 + lm,
  // d = ks*32 + quad*8 + j  (fp32 -> fp16; X unscaled)
  h16x8 A[8];
  const float* xrow = X + (size_t)(rowBase + wid * 16 + lm) * 256;
#pragma unroll
  for (int ks = 0; ks < 8; ++ks) {
    const int d0 = ks * 32 + quad * 8;
    float4 v0 = *(const float4*)(xrow + d0);
    float4 v1 = *(const float4*)(xrow + d0 + 4);
    h16x8 h;
    h[0] = (h16)v0.x; h[1] = (h16)v0.y; h[2] = (h16)v0.z; h[3] = (h16)v0.w;
    h[4] = (h16)v1.x; h[5] = (h16)v1.y; h[6] = (h16)v1.z; h[7] = (h16)v1.w;
    A[ks] = h;
  }

  f32x4 acc[8];
#pragma unroll
  for (int t = 0; t < 8; ++t) { f32x4 z = {0.f, 0.f, 0.f, 0.f}; acc[t] = z; }
  unsigned bestK[4];
#pragma unroll
  for (int r = 0; r < 4; ++r) bestK[r] = 0xFFFFFFFFu;

  __syncthreads();  // slice 0 resident (compiler drains vmcnt before barrier)

  // 32 slices: slice u = chunk (u>>2), ks-pair (u&3). One barrier per slice.
#pragma unroll 2
  for (int u = 0; u < 32; ++u) {
    const int buf = u & 1;
    if (u < 31) {  // stage next slice into the other buffer (async DMA)
      const h16* sbase = Whp2 + (size_t)(u + 1) * 8192;
#pragma unroll
      for (int i = 0; i < 4; ++i)
        gll16(sbase + (wid * 4 + i) * 512 + lane * 8, &Bs[buf ^ 1][(wid * 4 + i) * 512]);
    }
    // compute slice u: 2 ks x 8 n-tiles = 16 MFMAs per wave
#pragma unroll
    for (int ksl = 0; ksl < 2; ++ksl) {
      h16x8 a = A[(u & 3) * 2 + ksl];
#pragma unroll
      for (int t = 0; t < 8; ++t) {
        h16x8 b = *(const h16x8*)&Bs[buf][((ksl * 8 + t) * 64 + lane) * 8];
        acc[t] = __builtin_amdgcn_mfma_f32_16x16x32_f16(a, b, acc[t], 0, 0, 0);
      }
    }
    if ((u & 3) == 3) {  // chunk epilogue: fold biased scores into packed keys
      const int c = u >> 2;
#pragma unroll
      for (int t = 0; t < 8; ++t) {
        const int code = (c * 8 + t) * 16 + lm;
        const float wn = wws[code];
#pragma unroll
        for (int reg = 0; reg < 4; ++reg) {
          float s = fmaf(-W_UNSCALE2, acc[t][reg], wn);
          unsigned key = (__float_as_uint(s) & 0xFFFFFC00u) | (unsigned)code;
          bestK[reg] = min(bestK[reg], key);
        }
        f32x4 z = {0.f, 0.f, 0.f, 0.f};
        acc[t] = z;
      }
    }
    __syncthreads();  // stage(u+1) done + all waves finished reading buf
  }

  // wave-local argmin: reduce over the 16 lm columns (codes), rows stay put
#pragma unroll
  for (int m = 1; m <= 8; m <<= 1) {
#pragma unroll
    for (int reg = 0; reg < 4; ++reg)
      bestK[reg] = min(bestK[reg], (unsigned)__shfl_xor(bestK[reg], m));
  }
  if (lm == 0) {
#pragma unroll
    for (int reg = 0; reg < 4; ++reg) {
      const int row = wid * 16 + quad * 4 + reg;   // block-local row
      const int c = (int)(bestK[reg] & 1023u);
      sIdx[row] = c;
      atomicAdd(&counts[c], 1);
    }
  }
  __syncthreads();

  // output: out row = W[idx] (== x + sg(q-x) numerically); loss vs fp16 A regs
  const int myIdx = sIdx[wid * 16 + lm];
  const float* wrow = W + (size_t)myIdx * 256;
  float* orow = out + (size_t)(rowBase + wid * 16 + lm) * 256;
  float ll = 0.0f;
#pragma unroll
  for (int ks = 0; ks < 8; ++ks) {
    const int d0 = ks * 32 + quad * 8;
    float4 q0 = *(const float4*)(wrow + d0);
    float4 q1 = *(const float4*)(wrow + d0 + 4);
    h16x8 a = A[ks];
    float e0 = q0.x - (float)a[0], e1 = q0.y - (float)a[1];
    float e2 = q0.z - (float)a[2], e3 = q0.w - (float)a[3];
    float e4 = q1.x - (float)a[4], e5 = q1.y - (float)a[5];
    float e6 = q1.z - (float)a[6], e7 = q1.w - (float)a[7];
    ll += e0 * e0 + e1 * e1 + e2 * e2 + e3 * e3
        + e4 * e4 + e5 * e5 + e6 * e6 + e7 * e7;
    *(float4*)(orow + d0) = q0;
    *(float4*)(orow + d0 + 4) = q1;
  }
#pragma unroll
  for (int m = 1; m <= 32; m <<= 1) ll += __shfl_xor(ll, m);
  if (lane == 0) atomicAdd(loss_sum, ll);

  // fused finalize: last block computes loss + perplexity
  __threadfence();
  if (tid == 0) {
    int old = atomicAdd(done, 1);
    lastFlag = (old == (int)gridDim.x - 1);
  }
  __syncthreads();
  if (lastFlag) {
    float h = 0.0f;
#pragma unroll
    for (int k = tid; k < 1024; k += 256) {
      int cnt = __hip_atomic_load(&counts[k], __ATOMIC_RELAXED, __HIP_MEMORY_SCOPE_AGENT);
      float p = (float)cnt * (1.0f / 65536.0f);
      h += p * logf(p + 1e-10f);
    }
#pragma unroll
    for (int m = 1; m <= 32; m <<= 1) h += __shfl_xor(h, m);
    if (lane == 0) redF[wid] = h;
    __syncthreads();
    if (tid == 0) {
      float hs = redF[0] + redF[1] + redF[2] + redF[3];
      float ls = __hip_atomic_load(loss_sum, __ATOMIC_RELAXED, __HIP_MEMORY_SCOPE_AGENT);
      out[16777216] = ls * (1.25f / 16777216.0f);  // (1+0.25)*mean((q-x)^2)
      out[16777217] = expf(-hs);
    }
  }
}

// ---------------- launch ----------------
extern "C" void kernel_launch(void* const* d_in, const int* in_sizes, int n_in,
                              void* d_out, int out_size, void* d_ws, size_t ws_size,
                              hipStream_t stream) {
  (void)in_sizes; (void)n_in; (void)out_size; (void)ws_size;
  const float* X = (const float*)d_in[0];
  const float* W = (const float*)d_in[1];
  float* out = (float*)d_out;
  char* ws = (char*)d_ws;
  // ws layout (bytes): [0] loss_sum f32 | [4] done i32 | [256] counts i32[1024]
  //                    [4352] wws f32[1024] | [8448] Whp2 f16[262144]  => 532736 total
  float* loss_sum = (float*)ws;
  int* done = (int*)(ws + 4);
  int* counts = (int*)(ws + 256);
  float* wws = (float*)(ws + 4352);
  h16* Whp2 = (h16*)(ws + 8448);

  vq_wconv<<<512, 64, 0, stream>>>(W, Whp2, wws, (int*)ws);
  vq_main<<<1024, 256, 0, stream>>>(X, Whp2, wws, W, out, loss_sum, done, counts);
}